// Round 1
// baseline (542.541 us; speedup 1.0000x reference)
//
#include <hip/hip_runtime.h>

// UniformNeighborSampler:
//   out[i][j] = adj_info[ ids[i] ][ randpicks[i][j] ]
// adj_info: [N_NODES, MAX_DEGREE=128] int32
// ids:      [N_IDS]                 int32
// randpicks:[N_IDS, NS_COLS]        int32   (we use first num_samples cols)
// out:      [N_IDS, num_samples]    int32
//
// Pure gather, memory-latency-bound. One thread per output element:
// rp/out accesses coalesced; ids[i] broadcast across 10 consecutive lanes
// (L1-served); adj gather random -> L2/L3/HBM.

__global__ __launch_bounds__(256) void uniform_neighbor_sampler(
    const int* __restrict__ adj,       // [n_nodes, max_degree]
    const int* __restrict__ ids,       // [n_ids]
    const int* __restrict__ rp,        // [n_ids, rp_stride]
    int* __restrict__ out,             // [n_ids, num_samples]
    int n_out, int num_samples, int rp_stride, int max_degree)
{
    int t = blockIdx.x * blockDim.x + threadIdx.x;
    if (t >= n_out) return;
    int i = t / num_samples;
    int j = t - i * num_samples;
    int row = ids[i];
    int col = rp[i * rp_stride + j];
    out[t] = adj[(long long)row * max_degree + col];
}

extern "C" void kernel_launch(void* const* d_in, const int* in_sizes, int n_in,
                              void* d_out, int out_size, void* d_ws, size_t ws_size,
                              hipStream_t stream) {
    const int* adj = (const int*)d_in[0];
    const int* ids = (const int*)d_in[1];
    const int* rp  = (const int*)d_in[2];
    // d_in[3] is the python scalar num_samples (device-side, 1 element).
    // Derive everything shape-wise from sizes instead of reading device mem:
    int n_ids       = in_sizes[1];                 // 25,600
    int rp_stride   = in_sizes[2] / n_ids;         // 10 (NUM_SAMPLES cols)
    int num_samples = out_size / n_ids;            // 10
    const int max_degree = 128;                    // MAX_DEGREE in reference
    int* out = (int*)d_out;

    int n_out = out_size;
    int block = 256;
    int grid = (n_out + block - 1) / block;
    uniform_neighbor_sampler<<<grid, block, 0, stream>>>(
        adj, ids, rp, out, n_out, num_samples, rp_stride, max_degree);
}

// Round 2
// 542.357 us; speedup vs baseline: 1.0003x; 1.0003x over previous
//
#include <hip/hip_runtime.h>

// UniformNeighborSampler:
//   out[i][j] = adj_info[ ids[i] ][ randpicks[i][j] ]
// adj_info: [1M, 128] int32 (512 MB — exceeds 256 MB L3, gathers hit HBM)
// ids:      [25600]      int32
// randpicks:[25600, 10]  int32
// out:      [25600, 10]  int32
//
// Pure gather, latency/BW-bound on the random adj reads. Each thread handles
// TWO consecutive outputs of one row: int2 rp load + int2 out store
// (coalesced, 8B-aligned since row stride 10 ints and j even), two
// independent adj gathers in flight per thread.

__global__ __launch_bounds__(256) void uns_vec2(
    const int* __restrict__ adj,       // [n_nodes, 128]
    const int* __restrict__ ids,       // [n_ids]
    const int2* __restrict__ rp2,      // [n_ids * 5] viewed as int2 pairs
    int2* __restrict__ out2,           // [n_ids * 5]
    int n_pairs)                       // n_ids * num_samples / 2
{
    int t = blockIdx.x * blockDim.x + threadIdx.x;
    if (t >= n_pairs) return;
    int i = t / 5;                     // row (num_samples/2 == 5 pairs/row)
    int row = ids[i];
    const int* arow = adj + (long long)row * 128;
    int2 cols = rp2[t];                // coalesced 8B load
    int2 r;
    r.x = arow[cols.x];                // two independent random gathers
    r.y = arow[cols.y];
    out2[t] = r;                       // coalesced 8B store
}

// generic fallback (num_samples odd or stride mismatch)
__global__ __launch_bounds__(256) void uns_scalar(
    const int* __restrict__ adj, const int* __restrict__ ids,
    const int* __restrict__ rp, int* __restrict__ out,
    int n_out, int num_samples, int rp_stride)
{
    int t = blockIdx.x * blockDim.x + threadIdx.x;
    if (t >= n_out) return;
    int i = t / num_samples;
    int j = t - i * num_samples;
    out[t] = adj[(long long)ids[i] * 128 + rp[i * rp_stride + j]];
}

extern "C" void kernel_launch(void* const* d_in, const int* in_sizes, int n_in,
                              void* d_out, int out_size, void* d_ws, size_t ws_size,
                              hipStream_t stream) {
    const int* adj = (const int*)d_in[0];
    const int* ids = (const int*)d_in[1];
    const int* rp  = (const int*)d_in[2];
    int n_ids       = in_sizes[1];                 // 25,600
    int rp_stride   = in_sizes[2] / n_ids;         // 10
    int num_samples = out_size / n_ids;            // 10
    int* out = (int*)d_out;

    if (num_samples == 10 && rp_stride == 10) {
        int n_pairs = out_size / 2;                // 128,000
        int block = 256;
        int grid = (n_pairs + block - 1) / block;  // 500
        uns_vec2<<<grid, block, 0, stream>>>(
            adj, ids, (const int2*)rp, (int2*)out, n_pairs);
    } else {
        int block = 256;
        int grid = (out_size + block - 1) / block;
        uns_scalar<<<grid, block, 0, stream>>>(
            adj, ids, rp, out, out_size, num_samples, rp_stride);
    }
}